// Round 11
// baseline (429.798 us; speedup 1.0000x reference)
//
#include <hip/hip_runtime.h>
#include <hip/hip_bf16.h>

static constexpr int M_TOT = 8192;   // 4 * 2048
static constexpr int N_TOT = 4096;   // OUT_F
static constexpr int K_TOT = 4096;   // IN_F

static constexpr int BM = 256, BN = 256, BK = 32;
static constexpr int NT = K_TOT / BK;        // 128 K-tiles
static constexpr int GTHREADS = 512;         // 8 waves (2 M x 4 N)
static constexpr int BUF_BYTES = 32768;      // A 16K + B 16K per K-tile buffer
static constexpr int LDS_BYTES = 4 * BUF_BYTES;  // ring-4 = 128 KiB

typedef __bf16 bf16x8 __attribute__((ext_vector_type(8)));
typedef float f32x4 __attribute__((ext_vector_type(4)));
typedef unsigned short u16x8 __attribute__((ext_vector_type(8)));

__device__ __forceinline__ unsigned short f2bf(float f) {
  return __builtin_bit_cast(unsigned short, (__bf16)f);
}

// FP4 E2M1 decode: mag 0..7 -> 0,0.5,1,1.5,2,3,4,6 ; bit 3 = sign
__device__ __forceinline__ float fp4_decode(int idx) {
  unsigned u = (unsigned)idx & 15u;
  unsigned sgn = (u >> 3) << 31;
  unsigned mag = u & 7u;
  unsigned e = mag >> 1, m = mag & 1u;
  unsigned bits = (e == 0u) ? (m ? 0x3F000000u : 0u)
                            : (((126u + e) << 23) | (m << 22));
  return __uint_as_float(bits | sgn);
}

__device__ __forceinline__ void glds16(const void* g, void* l) {
  __builtin_amdgcn_global_load_lds(
      (__attribute__((address_space(1))) void*)g,
      (__attribute__((address_space(3))) void*)l, 16, 0, 0);
}

// ---- prepass (W only): int32 idx + scales -> bf16 W [N][K] ------------------
__global__ __launch_bounds__(256) void dequant_w_kernel(
    const int* __restrict__ idx, const float* __restrict__ scales,
    unsigned short* __restrict__ W) {
  const int t = blockIdx.x * 256 + threadIdx.x;  // 4 indices per thread
  const int4 v = reinterpret_cast<const int4*>(idx)[t];
  const float s = scales[t >> 2];
  ushort4 o;
  o.x = f2bf(fp4_decode(v.x) * s);
  o.y = f2bf(fp4_decode(v.y) * s);
  o.z = f2bf(fp4_decode(v.z) * s);
  o.w = f2bf(fp4_decode(v.w) * s);
  reinterpret_cast<ushort4*>(W)[t] = o;
}

// ---- GEMM: R3 schedule + fused A-conversion (fp32 x -> bf16 in reg-staging).
// A-path: PH_A(t) issues 4x global_load_dwordx4 of A(t+4) fp32 (T14 issue-
// early); after MFMA, VM(6) => A(t+3) landed AND B(t+1) landed; cvt + 2x
// ds_write_b128 of A(t+3); lgkmcnt(0) before BAR (cross-wave visibility).
// B-path unchanged (global_load_lds). Ring-4, zero-conflict involution layout.
__global__ __launch_bounds__(GTHREADS, 1) void gemm256(
    const float* __restrict__ X, const unsigned short* __restrict__ B,
    const float* __restrict__ bias, float* __restrict__ out) {
  extern __shared__ char smem[];

  const int t = threadIdx.x;
  const int lane = t & 63, wid = t >> 6;
  const int wr = wid >> 2;          // 0..1 (M half)
  const int wc = wid & 3;           // 0..3 (N quarter)
  const int ln = lane & 15;
  const int kc = lane >> 4;         // 0..3 k-chunk of 8 bf16

  // T1: XCD swizzle (512 blocks, 8 XCDs)
  const int bid = blockIdx.x;
  const int bmi = (bid & 7) * 4 + ((bid >> 3) & 3);  // 0..31
  const int bni = bid >> 5;                          // 0..15
  const int bm0 = bmi * BM, bn0 = bni * BN;

  // staging: thread t owns 16B-bf16 chunk (row t>>2, k-chunk kcd) per half;
  // source k-chunk pre-swizzled (involution c' = c ^ ((row>>1)&3))
  const int row_s = t >> 2;                   // 0..127
  const int kcd = (t & 3) ^ ((t >> 3) & 3);   // pre-swizzled global k-chunk
  const float* gxA = X + (size_t)(bm0 + row_s) * K_TOT + kcd * 8;   // fp32 A
  const unsigned short* gB = B + (size_t)(bn0 + row_s) * K_TOT + kcd * 8;
  char* ldsB = smem + 16384 + t * 16;

  // ds_read side: same involution ((row>>1)&3 == (ln>>1)&3, rows mult of 16)
  const int swz = (kc ^ ((ln >> 1) & 3)) * 16;
  const int base_a = (wr * 128 + ln) * 64 + swz;
  const int base_b = 16384 + (wc * 64 + ln) * 64 + swz;

  f32x4 acc[8][4];
#pragma unroll
  for (int i = 0; i < 8; ++i)
#pragma unroll
    for (int j = 0; j < 4; ++j) acc[i][j] = f32x4{0.f, 0.f, 0.f, 0.f};

  bf16x8 afA[4], afB[4], bfE[4], bfO[4];
  float4 ldE[4], ldO[4];   // in-flight fp32 A chunks (parity double-buffer)

#define LD_A(dst, kt) do {                                              \
    const float* q_ = gxA + (size_t)(kt) * BK;                          \
    dst[0] = *(const float4*)(q_);                                      \
    dst[1] = *(const float4*)(q_ + 4);                                  \
    dst[2] = *(const float4*)(q_ + (size_t)128 * K_TOT);                \
    dst[3] = *(const float4*)(q_ + (size_t)128 * K_TOT + 4);            \
  } while (0)

#define WR_A(src, bufi) do {                                            \
    u16x8 lo_, hi_;                                                     \
    lo_[0] = f2bf(src[0].x); lo_[1] = f2bf(src[0].y);                   \
    lo_[2] = f2bf(src[0].z); lo_[3] = f2bf(src[0].w);                   \
    lo_[4] = f2bf(src[1].x); lo_[5] = f2bf(src[1].y);                   \
    lo_[6] = f2bf(src[1].z); lo_[7] = f2bf(src[1].w);                   \
    hi_[0] = f2bf(src[2].x); hi_[1] = f2bf(src[2].y);                   \
    hi_[2] = f2bf(src[2].z); hi_[3] = f2bf(src[2].w);                   \
    hi_[4] = f2bf(src[3].x); hi_[5] = f2bf(src[3].y);                   \
    hi_[6] = f2bf(src[3].z); hi_[7] = f2bf(src[3].w);                   \
    *reinterpret_cast<u16x8*>(smem + (bufi) * BUF_BYTES + t * 16) = lo_; \
    *reinterpret_cast<u16x8*>(smem + (bufi) * BUF_BYTES + 8192 + t * 16) = hi_; \
  } while (0)

#define STAGE_B(kt, bufi) do {                                          \
    const unsigned short* s_ = gB + (size_t)(kt) * BK;                  \
    glds16(s_, ldsB + (bufi) * BUF_BYTES);                              \
    glds16(s_ + (size_t)128 * K_TOT, ldsB + (bufi) * BUF_BYTES + 8192); \
  } while (0)

#define READ_AF(dst, bufi, mb) do {                                     \
    const char* p_ = smem + (bufi) * BUF_BYTES + base_a + (mb) * 1024;  \
    dst[0] = *(const bf16x8*)(p_);                                      \
    dst[1] = *(const bf16x8*)(p_ + 1024);                               \
    dst[2] = *(const bf16x8*)(p_ + 2048);                               \
    dst[3] = *(const bf16x8*)(p_ + 3072);                               \
  } while (0)
#define READ_BF(dst, bufi) do {                                         \
    const char* p_ = smem + (bufi) * BUF_BYTES + base_b;                \
    dst[0] = *(const bf16x8*)(p_);                                      \
    dst[1] = *(const bf16x8*)(p_ + 1024);                               \
    dst[2] = *(const bf16x8*)(p_ + 2048);                               \
    dst[3] = *(const bf16x8*)(p_ + 3072);                               \
  } while (0)

#define MFMA16(afs, bfs, mb) do {                                       \
    __builtin_amdgcn_s_setprio(1);                                      \
    _Pragma("unroll")                                                   \
    for (int m_ = 0; m_ < 4; ++m_)                                      \
      _Pragma("unroll")                                                 \
      for (int n_ = 0; n_ < 4; ++n_)                                    \
        acc[(mb) + m_][n_] = __builtin_amdgcn_mfma_f32_16x16x32_bf16(   \
            afs[m_], bfs[n_], acc[(mb) + m_][n_], 0, 0, 0);             \
    __builtin_amdgcn_s_setprio(0);                                      \
  } while (0)

#define VM(n) asm volatile("s_waitcnt vmcnt(" #n ")" ::: "memory")
#define LGKM0 asm volatile("s_waitcnt lgkmcnt(0)" ::: "memory")
#define BAR __builtin_amdgcn_s_barrier()

  // Phase A of tile tt: issue A(tt+4) fp32 loads -> ldN ; read af m4-7 of tt ;
  // MFMA rows 0-3 ; VM(6) [A(tt+3) + B(tt+1) landed] ; write A(tt+3) from
  // ldW ; lgkm drain ; barrier.
#define PH_A(tt, rb, sb, bfc, ldN, ldW) do { \
    LD_A(ldN, (tt) + 4);       \
    READ_AF(afB, rb, 4);       \
    MFMA16(afA, bfc, 0);       \
    VM(6);                     \
    WR_A(ldW, sb);             \
    LGKM0; BAR;                \
  } while (0)
  // Phase B of tile tt: read-ahead af m0-3 + bf of tile tt+1 (landed),
  // stage B(tt+3) via glds, MFMA rows 4-7, barrier.
#define PH_B(tt, rbn, sb, bfc, bfn) do { \
    READ_AF(afA, rbn, 0);                \
    READ_BF(bfn, rbn);                   \
    STAGE_B((tt) + 3, sb);               \
    MFMA16(afB, bfc, 4);                 \
    BAR;                                 \
  } while (0)

  // ---- prologue: A0-2 written serially; B0-2 glds; A3 preloaded -> ldO
  LD_A(ldE, 0); VM(0); WR_A(ldE, 0);
  LD_A(ldE, 1); VM(0); WR_A(ldE, 1);
  LD_A(ldE, 2); VM(0); WR_A(ldE, 2);
  STAGE_B(0, 0);
  asm volatile("" ::: "memory");
  STAGE_B(1, 1);
  asm volatile("" ::: "memory");
  STAGE_B(2, 2);
  LD_A(ldO, 3);
  VM(6);   // queue [B0,B0,B1,B1,B2,B2,A3x4]: leaves B2x2+A3x4 => B0,B1 landed
  LGKM0;   // A-writes visible before barrier
  BAR;
  READ_AF(afA, 0, 0);
  READ_BF(bfE, 0);

  // ---- main loop: tiles 0..123 (4-tile unroll; ldE/ldO parity static)
#pragma unroll 1
  for (int tt = 0; tt < NT - 4; tt += 4) {
    PH_A(tt + 0, 0, 3, bfE, ldE, ldO);   // load A(tt+4)->ldE, write A(tt+3) from ldO
    PH_B(tt + 0, 1, 3, bfE, bfO);
    PH_A(tt + 1, 1, 0, bfO, ldO, ldE);
    PH_B(tt + 1, 2, 0, bfO, bfE);
    PH_A(tt + 2, 2, 1, bfE, ldE, ldO);
    PH_B(tt + 2, 3, 1, bfE, bfO);
    PH_A(tt + 3, 3, 2, bfO, ldO, ldE);
    PH_B(tt + 3, 0, 2, bfO, bfE);
  }

  // ---- tail: tiles 124..127 (A(127) in ldO from PH_A(123); drain 2 -> 0)
  // tile 124 (buf0): write A(127)->buf3; stage B(127)->buf3
  READ_AF(afB, 0, 4);
  MFMA16(afA, bfE, 0);
  VM(2);              // leaves B(126)x2 => A(127) landed; B(125) landed
  WR_A(ldO, 3);
  LGKM0; BAR;
  READ_AF(afA, 1, 0); READ_BF(bfO, 1); STAGE_B(127, 3); MFMA16(afB, bfE, 4); BAR;
  // tile 125 (buf1): allow B(127)x2 outstanding => B(126) landed
  READ_AF(afB, 1, 4); MFMA16(afA, bfO, 0); VM(2); BAR;
  READ_AF(afA, 2, 0); READ_BF(bfE, 2); MFMA16(afB, bfO, 4); BAR;
  // tile 126 (buf2): drain all => B(127) landed
  READ_AF(afB, 2, 4); MFMA16(afA, bfE, 0); VM(0); BAR;
  READ_AF(afA, 3, 0); READ_BF(bfO, 3); MFMA16(afB, bfE, 4); BAR;
  // tile 127 (buf3)
  READ_AF(afB, 3, 4); MFMA16(afA, bfO, 0);
  MFMA16(afB, bfO, 4);

  // ---- epilogue: C/D layout col = lane&15, row = (lane>>4)*4 + q
  const int orow0 = bm0 + wr * 128 + (lane >> 4) * 4;
  const int ocol0 = bn0 + wc * 64 + ln;
  float bj[4];
#pragma unroll
  for (int n = 0; n < 4; ++n) bj[n] = bias[ocol0 + n * 16];
#pragma unroll
  for (int mi = 0; mi < 8; ++mi)
#pragma unroll
    for (int n = 0; n < 4; ++n)
#pragma unroll
      for (int q = 0; q < 4; ++q)
        out[(size_t)(orow0 + mi * 16 + q) * N_TOT + ocol0 + n * 16] =
            acc[mi][n][q] + bj[n];
}

extern "C" void kernel_launch(void* const* d_in, const int* in_sizes, int n_in,
                              void* d_out, int out_size, void* d_ws, size_t ws_size,
                              hipStream_t stream) {
  const float* x = (const float*)d_in[0];
  const int* widx = (const int*)d_in[1];
  const float* wsc = (const float*)d_in[2];
  const float* bias = (const float*)d_in[3];
  float* out = (float*)d_out;

  unsigned short* Wbf = (unsigned short*)d_ws;   // 32 MiB bf16 W

  dequant_w_kernel<<<dim3((N_TOT * (size_t)K_TOT / 4) / 256), dim3(256), 0, stream>>>(
      widx, wsc, Wbf);

  (void)hipFuncSetAttribute((const void*)gemm256,
                            hipFuncAttributeMaxDynamicSharedMemorySize, LDS_BYTES);
  gemm256<<<dim3((M_TOT / BM) * (N_TOT / BN)), dim3(GTHREADS), LDS_BYTES, stream>>>(
      x, Wbf, bias, out);
}

// Round 12
// 290.600 us; speedup vs baseline: 1.4790x; 1.4790x over previous
//
#include <hip/hip_runtime.h>
#include <hip/hip_bf16.h>

static constexpr int M_TOT = 8192;   // 4 * 2048
static constexpr int N_TOT = 4096;   // OUT_F
static constexpr int K_TOT = 4096;   // IN_F

static constexpr int BM = 256, BN = 256, BK = 32;
static constexpr int NT = K_TOT / BK;        // 128 K-tiles
static constexpr int GTHREADS = 512;         // 8 waves (2 M x 4 N)
static constexpr int BUF_BYTES = 32768;      // A 16K + B 16K per K-tile buffer
static constexpr int LDS_BYTES = 4 * BUF_BYTES;  // ring-4 = 128 KiB

typedef __bf16 bf16x8 __attribute__((ext_vector_type(8)));
typedef float f32x4 __attribute__((ext_vector_type(4)));
typedef unsigned short u16x8 __attribute__((ext_vector_type(8)));
// global-addrspace fp32x4 pointer: forces global_load_dwordx4 (NOT flat_load,
// which would pollute lgkmcnt — R11 postmortem)
typedef const __attribute__((address_space(1))) f32x4* gf4p;

__device__ __forceinline__ unsigned short f2bf(float f) {
  return __builtin_bit_cast(unsigned short, (__bf16)f);
}

// FP4 E2M1 decode: mag 0..7 -> 0,0.5,1,1.5,2,3,4,6 ; bit 3 = sign
__device__ __forceinline__ float fp4_decode(int idx) {
  unsigned u = (unsigned)idx & 15u;
  unsigned sgn = (u >> 3) << 31;
  unsigned mag = u & 7u;
  unsigned e = mag >> 1, m = mag & 1u;
  unsigned bits = (e == 0u) ? (m ? 0x3F000000u : 0u)
                            : (((126u + e) << 23) | (m << 22));
  return __uint_as_float(bits | sgn);
}

__device__ __forceinline__ void glds16(const void* g, void* l) {
  __builtin_amdgcn_global_load_lds(
      (__attribute__((address_space(1))) void*)g,
      (__attribute__((address_space(3))) void*)l, 16, 0, 0);
}

// ---- prepass (W only): int32 idx + scales -> bf16 W [N][K] ------------------
__global__ __launch_bounds__(256) void dequant_w_kernel(
    const int* __restrict__ idx, const float* __restrict__ scales,
    unsigned short* __restrict__ W) {
  const int t = blockIdx.x * 256 + threadIdx.x;  // 4 indices per thread
  const int4 v = reinterpret_cast<const int4*>(idx)[t];
  const float s = scales[t >> 2];
  ushort4 o;
  o.x = f2bf(fp4_decode(v.x) * s);
  o.y = f2bf(fp4_decode(v.y) * s);
  o.z = f2bf(fp4_decode(v.z) * s);
  o.w = f2bf(fp4_decode(v.w) * s);
  reinterpret_cast<ushort4*>(W)[t] = o;
}

// ---- GEMM: R3 schedule + fused A-conversion (fp32 x -> bf16 reg-staged).
// A-path: PH_A(t) issues 4x global_load_dwordx4 (addrspace(1)!) of A(t+4);
// after MFMA, VM(6) => A(t+3) + B(t+1) landed; cvt + 2x ds_write_b128 of
// A(t+3); lgkmcnt(0) (ds only now) ; barrier. B-path: global_load_lds.
// Ring-4, zero-conflict involution layout, bijective XCD swizzle.
__global__ __launch_bounds__(GTHREADS, 1) void gemm256(
    const float* __restrict__ X, const unsigned short* __restrict__ B,
    const float* __restrict__ bias, float* __restrict__ out) {
  extern __shared__ char smem[];

  const int t = threadIdx.x;
  const int lane = t & 63, wid = t >> 6;
  const int wr = wid >> 2;          // 0..1 (M half)
  const int wc = wid & 3;           // 0..3 (N quarter)
  const int ln = lane & 15;
  const int kc = lane >> 4;         // 0..3 k-chunk of 8 bf16

  // T1: XCD swizzle (512 blocks, 8 XCDs)
  const int bid = blockIdx.x;
  const int bmi = (bid & 7) * 4 + ((bid >> 3) & 3);  // 0..31
  const int bni = bid >> 5;                          // 0..15
  const int bm0 = bmi * BM, bn0 = bni * BN;

  // staging: thread t owns 16B-bf16 chunk (row t>>2, k-chunk kcd) per half;
  // source k-chunk pre-swizzled (involution c' = c ^ ((row>>1)&3))
  const int row_s = t >> 2;                   // 0..127
  const int kcd = (t & 3) ^ ((t >> 3) & 3);   // pre-swizzled global k-chunk
  const float* gxA = X + (size_t)(bm0 + row_s) * K_TOT + kcd * 8;   // fp32 A
  const unsigned short* gB = B + (size_t)(bn0 + row_s) * K_TOT + kcd * 8;
  char* ldsB = smem + 16384 + t * 16;

  // ds_read side: same involution ((row>>1)&3 == (ln>>1)&3, rows mult of 16)
  const int swz = (kc ^ ((ln >> 1) & 3)) * 16;
  const int base_a = (wr * 128 + ln) * 64 + swz;
  const int base_b = 16384 + (wc * 64 + ln) * 64 + swz;

  f32x4 acc[8][4];
#pragma unroll
  for (int i = 0; i < 8; ++i)
#pragma unroll
    for (int j = 0; j < 4; ++j) acc[i][j] = f32x4{0.f, 0.f, 0.f, 0.f};

  bf16x8 afA[4], afB[4], bfE[4], bfO[4];
  f32x4 ldE[4], ldO[4];   // in-flight fp32 A chunks (parity double-buffer)

#define LD_A(dst, kt) do {                                              \
    const float* q_ = gxA + (size_t)(kt) * BK;                          \
    const float* r_ = q_ + (size_t)128 * K_TOT;                         \
    dst[0] = ((gf4p)(q_))[0];                                           \
    dst[1] = ((gf4p)(q_))[1];                                           \
    dst[2] = ((gf4p)(r_))[0];                                           \
    dst[3] = ((gf4p)(r_))[1];                                           \
  } while (0)

#define WR_A(src, bufi) do {                                            \
    u16x8 lo_, hi_;                                                     \
    lo_[0] = f2bf(src[0][0]); lo_[1] = f2bf(src[0][1]);                 \
    lo_[2] = f2bf(src[0][2]); lo_[3] = f2bf(src[0][3]);                 \
    lo_[4] = f2bf(src[1][0]); lo_[5] = f2bf(src[1][1]);                 \
    lo_[6] = f2bf(src[1][2]); lo_[7] = f2bf(src[1][3]);                 \
    hi_[0] = f2bf(src[2][0]); hi_[1] = f2bf(src[2][1]);                 \
    hi_[2] = f2bf(src[2][2]); hi_[3] = f2bf(src[2][3]);                 \
    hi_[4] = f2bf(src[3][0]); hi_[5] = f2bf(src[3][1]);                 \
    hi_[6] = f2bf(src[3][2]); hi_[7] = f2bf(src[3][3]);                 \
    *reinterpret_cast<u16x8*>(smem + (bufi) * BUF_BYTES + t * 16) = lo_; \
    *reinterpret_cast<u16x8*>(smem + (bufi) * BUF_BYTES + 8192 + t * 16) = hi_; \
  } while (0)

#define STAGE_B(kt, bufi) do {                                          \
    const unsigned short* s_ = gB + (size_t)(kt) * BK;                  \
    glds16(s_, ldsB + (bufi) * BUF_BYTES);                              \
    glds16(s_ + (size_t)128 * K_TOT, ldsB + (bufi) * BUF_BYTES + 8192); \
  } while (0)

#define READ_AF(dst, bufi, mb) do {                                     \
    const char* p_ = smem + (bufi) * BUF_BYTES + base_a + (mb) * 1024;  \
    dst[0] = *(const bf16x8*)(p_);                                      \
    dst[1] = *(const bf16x8*)(p_ + 1024);                               \
    dst[2] = *(const bf16x8*)(p_ + 2048);                               \
    dst[3] = *(const bf16x8*)(p_ + 3072);                               \
  } while (0)
#define READ_BF(dst, bufi) do {                                         \
    const char* p_ = smem + (bufi) * BUF_BYTES + base_b;                \
    dst[0] = *(const bf16x8*)(p_);                                      \
    dst[1] = *(const bf16x8*)(p_ + 1024);                               \
    dst[2] = *(const bf16x8*)(p_ + 2048);                               \
    dst[3] = *(const bf16x8*)(p_ + 3072);                               \
  } while (0)

#define MFMA16(afs, bfs, mb) do {                                       \
    __builtin_amdgcn_s_setprio(1);                                      \
    _Pragma("unroll")                                                   \
    for (int m_ = 0; m_ < 4; ++m_)                                      \
      _Pragma("unroll")                                                 \
      for (int n_ = 0; n_ < 4; ++n_)                                    \
        acc[(mb) + m_][n_] = __builtin_amdgcn_mfma_f32_16x16x32_bf16(   \
            afs[m_], bfs[n_], acc[(mb) + m_][n_], 0, 0, 0);             \
    __builtin_amdgcn_s_setprio(0);                                      \
  } while (0)

#define VM(n) asm volatile("s_waitcnt vmcnt(" #n ")" ::: "memory")
#define LGKM0 asm volatile("s_waitcnt lgkmcnt(0)" ::: "memory")
#define BAR __builtin_amdgcn_s_barrier()

  // Phase A of tile tt: issue A(tt+4) fp32 global loads -> ldN ; read af m4-7
  // of tt ; MFMA rows 0-3 ; VM(6) [A(tt+3) regs ready + B(tt+1) landed] ;
  // cvt+write A(tt+3) from ldW ; lgkm drain (ds only) ; barrier.
#define PH_A(tt, rb, sb, bfc, ldN, ldW) do { \
    LD_A(ldN, (tt) + 4);       \
    READ_AF(afB, rb, 4);       \
    MFMA16(afA, bfc, 0);       \
    VM(6);                     \
    WR_A(ldW, sb);             \
    LGKM0; BAR;                \
  } while (0)
  // Phase B of tile tt: read-ahead af m0-3 + bf of tile tt+1 (landed),
  // stage B(tt+3) via glds, MFMA rows 4-7, barrier.
#define PH_B(tt, rbn, sb, bfc, bfn) do { \
    READ_AF(afA, rbn, 0);                \
    READ_BF(bfn, rbn);                   \
    STAGE_B((tt) + 3, sb);               \
    MFMA16(afB, bfc, 4);                 \
    BAR;                                 \
  } while (0)

  // ---- prologue: A0-2 written serially; B0-2 glds; A3 preloaded -> ldO
  LD_A(ldE, 0); VM(0); WR_A(ldE, 0);
  LD_A(ldE, 1); VM(0); WR_A(ldE, 1);
  LD_A(ldE, 2); VM(0); WR_A(ldE, 2);
  STAGE_B(0, 0);
  asm volatile("" ::: "memory");
  STAGE_B(1, 1);
  asm volatile("" ::: "memory");
  STAGE_B(2, 2);
  LD_A(ldO, 3);
  VM(6);   // queue [B0x2,B1x2,B2x2,A3x4]: leaves B2x2+A3x4 => B0,B1 landed
  LGKM0;   // A-writes visible before barrier
  BAR;
  READ_AF(afA, 0, 0);
  READ_BF(bfE, 0);

  // ---- main loop: tiles 0..123 (4-tile unroll; ldE/ldO parity static)
#pragma unroll 1
  for (int tt = 0; tt < NT - 4; tt += 4) {
    PH_A(tt + 0, 0, 3, bfE, ldE, ldO);   // load A(tt+4)->ldE, write A(tt+3) from ldO
    PH_B(tt + 0, 1, 3, bfE, bfO);
    PH_A(tt + 1, 1, 0, bfO, ldO, ldE);
    PH_B(tt + 1, 2, 0, bfO, bfE);
    PH_A(tt + 2, 2, 1, bfE, ldE, ldO);
    PH_B(tt + 2, 3, 1, bfE, bfO);
    PH_A(tt + 3, 3, 2, bfO, ldO, ldE);
    PH_B(tt + 3, 0, 2, bfO, bfE);
  }

  // ---- tail: tiles 124..127 (A(127) in ldO from PH_A(123); drain 2 -> 0)
  // tile 124 (buf0): write A(127)->buf3; stage B(127)->buf3
  READ_AF(afB, 0, 4);
  MFMA16(afA, bfE, 0);
  VM(2);              // leaves B(126)x2 => A(127) regs ready; B(125) landed
  WR_A(ldO, 3);
  LGKM0; BAR;
  READ_AF(afA, 1, 0); READ_BF(bfO, 1); STAGE_B(127, 3); MFMA16(afB, bfE, 4); BAR;
  // tile 125 (buf1): allow B(127)x2 outstanding => B(126) landed
  READ_AF(afB, 1, 4); MFMA16(afA, bfO, 0); VM(2); BAR;
  READ_AF(afA, 2, 0); READ_BF(bfE, 2); MFMA16(afB, bfO, 4); BAR;
  // tile 126 (buf2): drain all => B(127) landed
  READ_AF(afB, 2, 4); MFMA16(afA, bfE, 0); VM(0); BAR;
  READ_AF(afA, 3, 0); READ_BF(bfO, 3); MFMA16(afB, bfE, 4); BAR;
  // tile 127 (buf3)
  READ_AF(afB, 3, 4); MFMA16(afA, bfO, 0);
  MFMA16(afB, bfO, 4);

  // ---- epilogue: C/D layout col = lane&15, row = (lane>>4)*4 + q
  const int orow0 = bm0 + wr * 128 + (lane >> 4) * 4;
  const int ocol0 = bn0 + wc * 64 + ln;
  float bj[4];
#pragma unroll
  for (int n = 0; n < 4; ++n) bj[n] = bias[ocol0 + n * 16];
#pragma unroll
  for (int mi = 0; mi < 8; ++mi)
#pragma unroll
    for (int n = 0; n < 4; ++n)
#pragma unroll
      for (int q = 0; q < 4; ++q)
        out[(size_t)(orow0 + mi * 16 + q) * N_TOT + ocol0 + n * 16] =
            acc[mi][n][q] + bj[n];
}

extern "C" void kernel_launch(void* const* d_in, const int* in_sizes, int n_in,
                              void* d_out, int out_size, void* d_ws, size_t ws_size,
                              hipStream_t stream) {
  const float* x = (const float*)d_in[0];
  const int* widx = (const int*)d_in[1];
  const float* wsc = (const float*)d_in[2];
  const float* bias = (const float*)d_in[3];
  float* out = (float*)d_out;

  unsigned short* Wbf = (unsigned short*)d_ws;   // 32 MiB bf16 W

  dequant_w_kernel<<<dim3((N_TOT * (size_t)K_TOT / 4) / 256), dim3(256), 0, stream>>>(
      widx, wsc, Wbf);

  (void)hipFuncSetAttribute((const void*)gemm256,
                            hipFuncAttributeMaxDynamicSharedMemorySize, LDS_BYTES);
  gemm256<<<dim3((M_TOT / BM) * (N_TOT / BN)), dim3(GTHREADS), LDS_BYTES, stream>>>(
      x, Wbf, bias, out);
}

// Round 13
// 279.569 us; speedup vs baseline: 1.5374x; 1.0395x over previous
//
#include <hip/hip_runtime.h>
#include <hip/hip_bf16.h>

static constexpr int M_TOT = 8192;   // 4 * 2048
static constexpr int N_TOT = 4096;   // OUT_F
static constexpr int K_TOT = 4096;   // IN_F

static constexpr int BM = 256, BN = 256, BK = 32;
static constexpr int NT = K_TOT / BK;        // 128 K-tiles
static constexpr int GTHREADS = 512;         // 8 waves (2 M x 4 N)
static constexpr int BUF_BYTES = 32768;      // A 16K + B 16K per K-tile buffer
static constexpr int LDS_BYTES = 4 * BUF_BYTES;  // ring-4 = 128 KiB

typedef __bf16 bf16x8 __attribute__((ext_vector_type(8)));
typedef float f32x4 __attribute__((ext_vector_type(4)));
typedef unsigned short u16x8 __attribute__((ext_vector_type(8)));
// global-addrspace fp32x4 pointer: forces global_load_dwordx4 (NOT flat_load,
// which pollutes lgkmcnt — R11 postmortem)
typedef const __attribute__((address_space(1))) f32x4* gf4p;

__device__ __forceinline__ unsigned short f2bf(float f) {
  return __builtin_bit_cast(unsigned short, (__bf16)f);
}

// FP4 E2M1 decode: mag 0..7 -> 0,0.5,1,1.5,2,3,4,6 ; bit 3 = sign
__device__ __forceinline__ float fp4_decode(int idx) {
  unsigned u = (unsigned)idx & 15u;
  unsigned sgn = (u >> 3) << 31;
  unsigned mag = u & 7u;
  unsigned e = mag >> 1, m = mag & 1u;
  unsigned bits = (e == 0u) ? (m ? 0x3F000000u : 0u)
                            : (((126u + e) << 23) | (m << 22));
  return __uint_as_float(bits | sgn);
}

__device__ __forceinline__ void glds16(const void* g, void* l) {
  __builtin_amdgcn_global_load_lds(
      (__attribute__((address_space(1))) void*)g,
      (__attribute__((address_space(3))) void*)l, 16, 0, 0);
}

// ---- prepass (W only): int32 idx + scales -> bf16 W [N][K] ------------------
__global__ __launch_bounds__(256) void dequant_w_kernel(
    const int* __restrict__ idx, const float* __restrict__ scales,
    unsigned short* __restrict__ W) {
  const int t = blockIdx.x * 256 + threadIdx.x;  // 4 indices per thread
  const int4 v = reinterpret_cast<const int4*>(idx)[t];
  const float s = scales[t >> 2];
  ushort4 o;
  o.x = f2bf(fp4_decode(v.x) * s);
  o.y = f2bf(fp4_decode(v.y) * s);
  o.z = f2bf(fp4_decode(v.z) * s);
  o.w = f2bf(fp4_decode(v.w) * s);
  reinterpret_cast<ushort4*>(W)[t] = o;
}

// ---- GEMM: R3 schedule + fused A-conversion, DEPTH-4 A-prefetch (R12 fix).
// A(k): loaded at PH_A(k-3) (global_load_dwordx4), written to LDS at
// PH_A(k-1) (latest legal: first read is PH_B(k-1) read-ahead, one BAR later).
// Load-to-gate distance = 4 phases >> HBM latency. Dual parity regs suffice:
// slot (k-3)%2 == (k-1)%2. Gates: steady VM(6) = A(t+2)x4 + B(t+2)x2 allowed,
// forcing A(t+1) regs + B(t+1) LDS. B-path: global_load_lds (unchanged).
__global__ __launch_bounds__(GTHREADS, 1) void gemm256(
    const float* __restrict__ X, const unsigned short* __restrict__ B,
    const float* __restrict__ bias, float* __restrict__ out) {
  extern __shared__ char smem[];

  const int t = threadIdx.x;
  const int lane = t & 63, wid = t >> 6;
  const int wr = wid >> 2;          // 0..1 (M half)
  const int wc = wid & 3;           // 0..3 (N quarter)
  const int ln = lane & 15;
  const int kc = lane >> 4;         // 0..3 k-chunk of 8 bf16

  // T1: XCD swizzle (512 blocks, 8 XCDs)
  const int bid = blockIdx.x;
  const int bmi = (bid & 7) * 4 + ((bid >> 3) & 3);  // 0..31
  const int bni = bid >> 5;                          // 0..15
  const int bm0 = bmi * BM, bn0 = bni * BN;

  // staging: thread t owns 16B-bf16 chunk (row t>>2, k-chunk kcd) per half;
  // source k-chunk pre-swizzled (involution c' = c ^ ((row>>1)&3))
  const int row_s = t >> 2;                   // 0..127
  const int kcd = (t & 3) ^ ((t >> 3) & 3);   // pre-swizzled global k-chunk
  const float* gxA = X + (size_t)(bm0 + row_s) * K_TOT + kcd * 8;   // fp32 A
  const unsigned short* gB = B + (size_t)(bn0 + row_s) * K_TOT + kcd * 8;
  char* ldsB = smem + 16384 + t * 16;

  // ds_read side: same involution ((row>>1)&3 == (ln>>1)&3, rows mult of 16)
  const int swz = (kc ^ ((ln >> 1) & 3)) * 16;
  const int base_a = (wr * 128 + ln) * 64 + swz;
  const int base_b = 16384 + (wc * 64 + ln) * 64 + swz;

  f32x4 acc[8][4];
#pragma unroll
  for (int i = 0; i < 8; ++i)
#pragma unroll
    for (int j = 0; j < 4; ++j) acc[i][j] = f32x4{0.f, 0.f, 0.f, 0.f};

  bf16x8 afA[4], afB[4], bfE[4], bfO[4];
  f32x4 ldE[4], ldO[4];   // in-flight fp32 A chunks (parity double-buffer)

#define LD_A(dst, kt) do {                                              \
    const float* q_ = gxA + (size_t)(kt) * BK;                          \
    const float* r_ = q_ + (size_t)128 * K_TOT;                         \
    dst[0] = ((gf4p)(q_))[0];                                           \
    dst[1] = ((gf4p)(q_))[1];                                           \
    dst[2] = ((gf4p)(r_))[0];                                           \
    dst[3] = ((gf4p)(r_))[1];                                           \
  } while (0)

#define WR_A(src, bufi) do {                                            \
    u16x8 lo_, hi_;                                                     \
    lo_[0] = f2bf(src[0][0]); lo_[1] = f2bf(src[0][1]);                 \
    lo_[2] = f2bf(src[0][2]); lo_[3] = f2bf(src[0][3]);                 \
    lo_[4] = f2bf(src[1][0]); lo_[5] = f2bf(src[1][1]);                 \
    lo_[6] = f2bf(src[1][2]); lo_[7] = f2bf(src[1][3]);                 \
    hi_[0] = f2bf(src[2][0]); hi_[1] = f2bf(src[2][1]);                 \
    hi_[2] = f2bf(src[2][2]); hi_[3] = f2bf(src[2][3]);                 \
    hi_[4] = f2bf(src[3][0]); hi_[5] = f2bf(src[3][1]);                 \
    hi_[6] = f2bf(src[3][2]); hi_[7] = f2bf(src[3][3]);                 \
    *reinterpret_cast<u16x8*>(smem + (bufi) * BUF_BYTES + t * 16) = lo_; \
    *reinterpret_cast<u16x8*>(smem + (bufi) * BUF_BYTES + 8192 + t * 16) = hi_; \
  } while (0)

#define STAGE_B(kt, bufi) do {                                          \
    const unsigned short* s_ = gB + (size_t)(kt) * BK;                  \
    glds16(s_, ldsB + (bufi) * BUF_BYTES);                              \
    glds16(s_ + (size_t)128 * K_TOT, ldsB + (bufi) * BUF_BYTES + 8192); \
  } while (0)

#define READ_AF(dst, bufi, mb) do {                                     \
    const char* p_ = smem + (bufi) * BUF_BYTES + base_a + (mb) * 1024;  \
    dst[0] = *(const bf16x8*)(p_);                                      \
    dst[1] = *(const bf16x8*)(p_ + 1024);                               \
    dst[2] = *(const bf16x8*)(p_ + 2048);                               \
    dst[3] = *(const bf16x8*)(p_ + 3072);                               \
  } while (0)
#define READ_BF(dst, bufi) do {                                         \
    const char* p_ = smem + (bufi) * BUF_BYTES + base_b;                \
    dst[0] = *(const bf16x8*)(p_);                                      \
    dst[1] = *(const bf16x8*)(p_ + 1024);                               \
    dst[2] = *(const bf16x8*)(p_ + 2048);                               \
    dst[3] = *(const bf16x8*)(p_ + 3072);                               \
  } while (0)

#define MFMA16(afs, bfs, mb) do {                                       \
    __builtin_amdgcn_s_setprio(1);                                      \
    _Pragma("unroll")                                                   \
    for (int m_ = 0; m_ < 4; ++m_)                                      \
      _Pragma("unroll")                                                 \
      for (int n_ = 0; n_ < 4; ++n_)                                    \
        acc[(mb) + m_][n_] = __builtin_amdgcn_mfma_f32_16x16x32_bf16(   \
            afs[m_], bfs[n_], acc[(mb) + m_][n_], 0, 0, 0);             \
    __builtin_amdgcn_s_setprio(0);                                      \
  } while (0)

#define VM(n) asm volatile("s_waitcnt vmcnt(" #n ")" ::: "memory")
#define LGKM0 asm volatile("s_waitcnt lgkmcnt(0)" ::: "memory")
#define BAR __builtin_amdgcn_s_barrier()

  // Phase A of tile tt: read af m4-7 of tt ; MFMA rows 0-3 ; VM(6) [A(tt+1)
  // regs ready + B(tt+1) landed] ; write A(tt+1) -> buf wb ; load A(tt+3)
  // into the freed slot ; lgkm drain (ds only) ; barrier.
#define PH_A(tt_, rb, wb, bfc, ld) do { \
    READ_AF(afB, rb, 4);                \
    MFMA16(afA, bfc, 0);                \
    VM(6);                              \
    WR_A(ld, wb);                       \
    LD_A(ld, (tt_) + 3);                \
    LGKM0; BAR;                         \
  } while (0)
  // Phase B of tile tt: read-ahead af m0-3 + bf of tile tt+1 (just written /
  // landed), stage B(tt+3) via glds, MFMA rows 4-7, barrier.
#define PH_B(tt_, rbn, sb, bfc, bfn) do { \
    READ_AF(afA, rbn, 0);                 \
    READ_BF(bfn, rbn);                    \
    STAGE_B((tt_) + 3, sb);               \
    MFMA16(afB, bfc, 4);                  \
    BAR;                                  \
  } while (0)

  // ---- prologue. Issue order is load-bearing for the vmcnt gates:
  // [B0x2] [B1x2] [A1x4] [A2x4] [B2x2]  (after A0 drained+written)
  LD_A(ldE, 0); VM(0); WR_A(ldE, 0);   // A0 -> buf0
  STAGE_B(0, 0);
  asm volatile("" ::: "memory");
  STAGE_B(1, 1);
  asm volatile("" ::: "memory");
  LD_A(ldO, 1);                         // A1: written at PH_A(0), slot 1
  asm volatile("" ::: "memory");
  LD_A(ldE, 2);                         // A2: written at PH_A(1), slot 0
  asm volatile("" ::: "memory");
  STAGE_B(2, 2);
  VM(12);  // allowed: B1x2+A1x4+A2x4+B2x2 => B0 landed
  LGKM0;   // A0 write visible
  BAR;
  READ_AF(afA, 0, 0);
  READ_BF(bfE, 0);

  // ---- main loop: tiles 0..123 (4-tile unroll; slots alternate per PH_A)
#pragma unroll 1
  for (int tt = 0; tt < 124; tt += 4) {
    PH_A(tt + 0, 0, 1, bfE, ldO);   // WR A(tt+1)->buf1, LD A(tt+3)
    PH_B(tt + 0, 1, 3, bfE, bfO);
    PH_A(tt + 1, 1, 2, bfO, ldE);
    PH_B(tt + 1, 2, 0, bfO, bfE);
    PH_A(tt + 2, 2, 3, bfE, ldO);
    PH_B(tt + 2, 3, 1, bfE, bfO);
    PH_A(tt + 3, 3, 0, bfO, ldE);
    PH_B(tt + 3, 0, 2, bfO, bfE);
  }
  // post-loop live: ldO = A(125) [PH_A(122)], ldE = A(126) [PH_A(123)]

  // ---- tail: tiles 124..127
  // tile 124 (buf0): WR A(125)->buf1; LD A(127) (real, slot ldO); stage B(127)
  READ_AF(afB, 0, 4);
  MFMA16(afA, bfE, 0);
  VM(6);               // allowed A(126)x4+B(126)x2 => A(125) regs, B(125) in
  WR_A(ldO, 1);
  LD_A(ldO, 127);
  LGKM0; BAR;
  READ_AF(afA, 1, 0); READ_BF(bfO, 1); STAGE_B(127, 3); MFMA16(afB, bfE, 4); BAR;
  // tile 125 (buf1): WR A(126)->buf2
  READ_AF(afB, 1, 4);
  MFMA16(afA, bfO, 0);
  VM(6);               // allowed A(127)x4+B(127)x2 => A(126) regs, B(126) in
  WR_A(ldE, 2);
  LGKM0; BAR;
  READ_AF(afA, 2, 0); READ_BF(bfE, 2); MFMA16(afB, bfO, 4); BAR;
  // tile 126 (buf2): WR A(127)->buf3; drain all
  READ_AF(afB, 2, 4);
  MFMA16(afA, bfE, 0);
  VM(0);               // A(127) regs + B(127) landed
  WR_A(ldO, 3);
  LGKM0; BAR;
  READ_AF(afA, 3, 0); READ_BF(bfO, 3); MFMA16(afB, bfE, 4); BAR;
  // tile 127 (buf3)
  READ_AF(afB, 3, 4);
  MFMA16(afA, bfO, 0);
  MFMA16(afB, bfO, 4);

  // ---- epilogue: C/D layout col = lane&15, row = (lane>>4)*4 + q
  const int orow0 = bm0 + wr * 128 + (lane >> 4) * 4;
  const int ocol0 = bn0 + wc * 64 + ln;
  float bj[4];
#pragma unroll
  for (int n = 0; n < 4; ++n) bj[n] = bias[ocol0 + n * 16];
#pragma unroll
  for (int mi = 0; mi < 8; ++mi)
#pragma unroll
    for (int n = 0; n < 4; ++n)
#pragma unroll
      for (int q = 0; q < 4; ++q)
        out[(size_t)(orow0 + mi * 16 + q) * N_TOT + ocol0 + n * 16] =
            acc[mi][n][q] + bj[n];
}

extern "C" void kernel_launch(void* const* d_in, const int* in_sizes, int n_in,
                              void* d_out, int out_size, void* d_ws, size_t ws_size,
                              hipStream_t stream) {
  const float* x = (const float*)d_in[0];
  const int* widx = (const int*)d_in[1];
  const float* wsc = (const float*)d_in[2];
  const float* bias = (const float*)d_in[3];
  float* out = (float*)d_out;

  unsigned short* Wbf = (unsigned short*)d_ws;   // 32 MiB bf16 W

  dequant_w_kernel<<<dim3((N_TOT * (size_t)K_TOT / 4) / 256), dim3(256), 0, stream>>>(
      widx, wsc, Wbf);

  (void)hipFuncSetAttribute((const void*)gemm256,
                            hipFuncAttributeMaxDynamicSharedMemorySize, LDS_BYTES);
  gemm256<<<dim3((M_TOT / BM) * (N_TOT / BN)), dim3(GTHREADS), LDS_BYTES, stream>>>(
      x, Wbf, bias, out);
}

// Round 14
// 274.529 us; speedup vs baseline: 1.5656x; 1.0184x over previous
//
#include <hip/hip_runtime.h>
#include <hip/hip_bf16.h>

static constexpr int M_TOT = 8192;   // 4 * 2048
static constexpr int N_TOT = 4096;   // OUT_F
static constexpr int K_TOT = 4096;   // IN_F

static constexpr int BM = 256, BN = 256, BK = 32;
static constexpr int NT = K_TOT / BK;        // 128 K-tiles
static constexpr int GTHREADS = 512;         // 8 waves (2 M x 4 N)
static constexpr int BUF_BYTES = 32768;      // A 16K + B 16K per K-tile buffer
static constexpr int LDS_BYTES = 4 * BUF_BYTES;  // ring-4 = 128 KiB

typedef __bf16 bf16x8 __attribute__((ext_vector_type(8)));
typedef float f32x4 __attribute__((ext_vector_type(4)));
typedef unsigned short u16x8 __attribute__((ext_vector_type(8)));

__device__ __forceinline__ unsigned short f2bf(float f) {
  return __builtin_bit_cast(unsigned short, (__bf16)f);
}

// FP4 E2M1 decode: mag 0..7 -> 0,0.5,1,1.5,2,3,4,6 ; bit 3 = sign
__device__ __forceinline__ float fp4_decode(int idx) {
  unsigned u = (unsigned)idx & 15u;
  unsigned sgn = (u >> 3) << 31;
  unsigned mag = u & 7u;
  unsigned e = mag >> 1, m = mag & 1u;
  unsigned bits = (e == 0u) ? (m ? 0x3F000000u : 0u)
                            : (((126u + e) << 23) | (m << 22));
  return __uint_as_float(bits | sgn);
}

__device__ __forceinline__ void glds16(const void* g, void* l) {
  __builtin_amdgcn_global_load_lds(
      (__attribute__((address_space(1))) void*)g,
      (__attribute__((address_space(3))) void*)l, 16, 0, 0);
}

// ---- merged prepass: blocks [0,16384) convert x->bf16 A; [16384,32768) W ----
__global__ __launch_bounds__(256) void prepass_kernel(
    const float* __restrict__ x, unsigned short* __restrict__ A,
    const int* __restrict__ idx, const float* __restrict__ scales,
    unsigned short* __restrict__ W) {
  const int b = blockIdx.x;
  if (b < 16384) {
    const int t = b * 256 + threadIdx.x;  // 8 floats per thread
    const float4* xp = reinterpret_cast<const float4*>(x);
    const float4 a = xp[2 * t], c = xp[2 * t + 1];
    u16x8 o;
    o[0] = f2bf(a.x); o[1] = f2bf(a.y); o[2] = f2bf(a.z); o[3] = f2bf(a.w);
    o[4] = f2bf(c.x); o[5] = f2bf(c.y); o[6] = f2bf(c.z); o[7] = f2bf(c.w);
    reinterpret_cast<u16x8*>(A)[t] = o;
  } else {
    const int t = (b - 16384) * 256 + threadIdx.x;  // 4 indices per thread
    const int4 v = reinterpret_cast<const int4*>(idx)[t];
    const float s = scales[t >> 2];
    ushort4 o;
    o.x = f2bf(fp4_decode(v.x) * s);
    o.y = f2bf(fp4_decode(v.y) * s);
    o.z = f2bf(fp4_decode(v.z) * s);
    o.w = f2bf(fp4_decode(v.w) * s);
    reinterpret_cast<ushort4*>(W)[t] = o;
  }
}

// ---- GEMM (R3/R10 champion, verbatim): 256x256, BK=32, ring-4 LDS, reg-dbuf
// frags, counted vmcnt. Measured: ~229 us, MfmaUtil ~58%, 0 conflicts. -------
__global__ __launch_bounds__(GTHREADS, 1) void gemm256(
    const unsigned short* __restrict__ A, const unsigned short* __restrict__ B,
    const float* __restrict__ bias, float* __restrict__ out) {
  extern __shared__ char smem[];

  const int t = threadIdx.x;
  const int lane = t & 63, wid = t >> 6;
  const int wr = wid >> 2;          // 0..1 (M half)
  const int wc = wid & 3;           // 0..3 (N quarter)
  const int ln = lane & 15;
  const int kc = lane >> 4;         // 0..3 k-chunk of 8 bf16

  // T1: XCD swizzle (512 blocks, 8 XCDs)
  const int bid = blockIdx.x;
  const int bmi = (bid & 7) * 4 + ((bid >> 3) & 3);  // 0..31
  const int bni = bid >> 5;                          // 0..15
  const int bm0 = bmi * BM, bn0 = bni * BN;

  // staging: thread t writes 16B chunk at linear LDS pos; source k-chunk
  // pre-swizzled (involution c' = c ^ ((row>>1)&3), rows are 64B)
  const int row_s = t >> 2;                   // 0..127
  const int kcd = (t & 3) ^ ((t >> 3) & 3);   // pre-swizzled global k-chunk
  const unsigned short* gA = A + (size_t)(bm0 + row_s) * K_TOT + kcd * 8;
  const unsigned short* gB = B + (size_t)(bn0 + row_s) * K_TOT + kcd * 8;
  char* ldsA = smem + t * 16;
  char* ldsB = smem + 16384 + t * 16;

  // ds_read side: same involution ((row>>1)&3 == (ln>>1)&3 since frag rows
  // differ by multiples of 16)
  const int swz = (kc ^ ((ln >> 1) & 3)) * 16;
  const int base_a = (wr * 128 + ln) * 64 + swz;
  const int base_b = 16384 + (wc * 64 + ln) * 64 + swz;

  f32x4 acc[8][4];
#pragma unroll
  for (int i = 0; i < 8; ++i)
#pragma unroll
    for (int j = 0; j < 4; ++j) acc[i][j] = f32x4{0.f, 0.f, 0.f, 0.f};

  bf16x8 afA[4], afB[4], bfE[4], bfO[4];

#define STAGE_A(kt, bufi) do {                                          \
    const unsigned short* s_ = gA + (size_t)(kt) * BK;                  \
    glds16(s_, ldsA + (bufi) * BUF_BYTES);                              \
    glds16(s_ + (size_t)128 * K_TOT, ldsA + (bufi) * BUF_BYTES + 8192); \
  } while (0)
#define STAGE_B(kt, bufi) do {                                          \
    const unsigned short* s_ = gB + (size_t)(kt) * BK;                  \
    glds16(s_, ldsB + (bufi) * BUF_BYTES);                              \
    glds16(s_ + (size_t)128 * K_TOT, ldsB + (bufi) * BUF_BYTES + 8192); \
  } while (0)

#define READ_AF(dst, bufi, mb) do {                                     \
    const char* p_ = smem + (bufi) * BUF_BYTES + base_a + (mb) * 1024;  \
    dst[0] = *(const bf16x8*)(p_);                                      \
    dst[1] = *(const bf16x8*)(p_ + 1024);                               \
    dst[2] = *(const bf16x8*)(p_ + 2048);                               \
    dst[3] = *(const bf16x8*)(p_ + 3072);                               \
  } while (0)
#define READ_BF(dst, bufi) do {                                         \
    const char* p_ = smem + (bufi) * BUF_BYTES + base_b;                \
    dst[0] = *(const bf16x8*)(p_);                                      \
    dst[1] = *(const bf16x8*)(p_ + 1024);                               \
    dst[2] = *(const bf16x8*)(p_ + 2048);                               \
    dst[3] = *(const bf16x8*)(p_ + 3072);                               \
  } while (0)

#define MFMA16(afs, bfs, mb) do {                                       \
    __builtin_amdgcn_s_setprio(1);                                      \
    _Pragma("unroll")                                                   \
    for (int m_ = 0; m_ < 4; ++m_)                                      \
      _Pragma("unroll")                                                 \
      for (int n_ = 0; n_ < 4; ++n_)                                    \
        acc[(mb) + m_][n_] = __builtin_amdgcn_mfma_f32_16x16x32_bf16(   \
            afs[m_], bfs[n_], acc[(mb) + m_][n_], 0, 0, 0);             \
    __builtin_amdgcn_s_setprio(0);                                      \
  } while (0)

#define VM(n) asm volatile("s_waitcnt vmcnt(" #n ")" ::: "memory")
#define BAR __builtin_amdgcn_s_barrier()

  // Phase A of tile tt (data in buf rb): read af m4-7 of tt, stage A(tt+3),
  // MFMA rows 0-3, then vmcnt(6) + barrier => tile tt+1 landed GLOBALLY.
#define PH_A(tt, rb, sb, bfc) do { \
    READ_AF(afB, rb, 4);           \
    STAGE_A((tt) + 3, sb);         \
    MFMA16(afA, bfc, 0);           \
    VM(6); BAR;                    \
  } while (0)
  // Phase B of tile tt: read-ahead af m0-3 + bf of tile tt+1 (safe: landed),
  // stage B(tt+3), MFMA rows 4-7, barrier.
#define PH_B(tt, rbn, sb, bfc, bfn) do { \
    READ_AF(afA, rbn, 0);                \
    READ_BF(bfn, rbn);                   \
    STAGE_B((tt) + 3, sb);               \
    MFMA16(afB, bfc, 4);                 \
    BAR;                                 \
  } while (0)

  // ---- prologue: stage tiles 0,1,2 (order pinned for vmcnt accounting)
  STAGE_A(0, 0); STAGE_B(0, 0);
  asm volatile("" ::: "memory");
  STAGE_A(1, 1); STAGE_B(1, 1);
  asm volatile("" ::: "memory");
  STAGE_A(2, 2); STAGE_B(2, 2);
  VM(8);  // tile 0 landed (own); barrier makes it global
  BAR;
  READ_AF(afA, 0, 0);
  READ_BF(bfE, 0);

  // ---- main loop: tiles 0..123, stages 3..126 (4-tile unroll, static bufs)
#pragma unroll 1
  for (int tt = 0; tt < NT - 4; tt += 4) {
    PH_A(tt + 0, 0, 3, bfE);
    PH_B(tt + 0, 1, 3, bfE, bfO);
    PH_A(tt + 1, 1, 0, bfO);
    PH_B(tt + 1, 2, 0, bfO, bfE);
    PH_A(tt + 2, 2, 1, bfE);
    PH_B(tt + 2, 3, 1, bfE, bfO);
    PH_A(tt + 3, 3, 2, bfO);
    PH_B(tt + 3, 0, 2, bfO, bfE);
  }

  // ---- tail: tiles 124..127, drain 6 -> 4 -> 0
  // tile 124 (buf0), stages tile 127 -> buf3
  READ_AF(afB, 0, 4); STAGE_A(127, 3); MFMA16(afA, bfE, 0); VM(6); BAR;
  READ_AF(afA, 1, 0); READ_BF(bfO, 1); STAGE_B(127, 3); MFMA16(afB, bfE, 4); BAR;
  // tile 125 (buf1): newest allowed = A(127)+B(127) = 4 => tile 126 landed
  READ_AF(afB, 1, 4); MFMA16(afA, bfO, 0); VM(4); BAR;
  READ_AF(afA, 2, 0); READ_BF(bfE, 2); MFMA16(afB, bfO, 4); BAR;
  // tile 126 (buf2): drain all => tile 127 landed
  READ_AF(afB, 2, 4); MFMA16(afA, bfE, 0); VM(0); BAR;
  READ_AF(afA, 3, 0); READ_BF(bfO, 3); MFMA16(afB, bfE, 4); BAR;
  // tile 127 (buf3)
  READ_AF(afB, 3, 4); MFMA16(afA, bfO, 0);
  MFMA16(afB, bfO, 4);

  // ---- epilogue: C/D layout col = lane&15, row = (lane>>4)*4 + q
  const int orow0 = bm0 + wr * 128 + (lane >> 4) * 4;
  const int ocol0 = bn0 + wc * 64 + ln;
  float bj[4];
#pragma unroll
  for (int n = 0; n < 4; ++n) bj[n] = bias[ocol0 + n * 16];
#pragma unroll
  for (int mi = 0; mi < 8; ++mi)
#pragma unroll
    for (int n = 0; n < 4; ++n)
#pragma unroll
      for (int q = 0; q < 4; ++q)
        out[(size_t)(orow0 + mi * 16 + q) * N_TOT + ocol0 + n * 16] =
            acc[mi][n][q] + bj[n];
}

extern "C" void kernel_launch(void* const* d_in, const int* in_sizes, int n_in,
                              void* d_out, int out_size, void* d_ws, size_t ws_size,
                              hipStream_t stream) {
  const float* x = (const float*)d_in[0];
  const int* widx = (const int*)d_in[1];
  const float* wsc = (const float*)d_in[2];
  const float* bias = (const float*)d_in[3];
  float* out = (float*)d_out;

  unsigned short* Abf = (unsigned short*)d_ws;                       // 64 MiB
  unsigned short* Wbf = (unsigned short*)((char*)d_ws + (size_t)M_TOT * K_TOT * 2);  // 32 MiB

  prepass_kernel<<<dim3(32768), dim3(256), 0, stream>>>(x, Abf, widx, wsc, Wbf);

  (void)hipFuncSetAttribute((const void*)gemm256,
                            hipFuncAttributeMaxDynamicSharedMemorySize, LDS_BYTES);
  gemm256<<<dim3((M_TOT / BM) * (N_TOT / BN)), dim3(GTHREADS), LDS_BYTES, stream>>>(
      Abf, Wbf, bias, out);
}